// Round 3
// baseline (471.952 us; speedup 1.0000x reference)
//
#include <hip/hip_runtime.h>
#include <hip/hip_fp16.h>
#include <hip/hip_cooperative_groups.h>

namespace cg = cooperative_groups;

#define NB   32
#define NN   1024
#define NBLK 256
#define NTHR 512

// ---------------- ws layout (floats unless noted) ----------------
static const size_t F_D     = 0;        // 32768  : rsqrt degree [B,N]
static const size_t F_STATS = 32768;    // 16384  : 8 x {sum[1024], sumsq[1024]}
static const size_t F_XW1   = 49152;    // 131072 : x @ W1  [B,N,4]
// Y raw relu outputs (cs = 4,2,4,2,4,2,4,2), fixed offsets:
static const size_t F_Y[8] = {180224, 311296, 376832, 507904,
                              573440, 704512, 770048, 901120};
static const size_t AH_BYTE_OFF  = 3866624;                 // fp16 adj(diag=1), 64MB
static const size_t WS_NEED_HALF = AH_BYTE_OFF + (size_t)NB*NN*NN*2;

struct KParams {
    const float *adj, *x, *W1, *b1, *W2, *b2, *W3, *b3, *W5, *b5, *W7, *b7, *Wl, *bl;
    float* out;
    float* wsf;
    __half* ah;
    int use_half;
};

// ------------------------------------------------------------------
// One propagation pass: Y = relu(Anorm @ XW + b), Anorm = d[r]*ahat[r][k]*d[k].
// d[k] folded into LDS XW tile; d[r] applied in epilogue.
// Block owns batch b = bid>>3 and a 128-row slab t0 = (bid&7)*128.
// LDS XP padded: word m(k) = k + 4*(k>>5) -> conflict-free ds_read_b128.
template<int CIN1, int CIN2, int COUT, bool HALFA>
__device__ __forceinline__ void do_pass(
    const int bid, const int tid,
    const float* __restrict__ adj, const __half* __restrict__ ah,
    const float* __restrict__ dd, const float* __restrict__ xw1,
    const float* __restrict__ src1, const float* __restrict__ st1,
    const float* __restrict__ src2, const float* __restrict__ st2,
    const float* __restrict__ W, const float* __restrict__ bias,
    float* __restrict__ Y, float* __restrict__ stout,
    float XP[4][NN + (NN/32)*4])
{
    const int b  = bid >> 3;
    const int t0 = (bid & 7) << 7;

    // ---- prologue: build XW tile (d[k] folded) ----
    for (int k = tid; k < NN; k += NTHR) {
        float xw[COUT];
        if constexpr (CIN1 == 0) {
            const float4 v = *(const float4*)(xw1 + ((size_t)b*NN + k) * 4);
            xw[0]=v.x; xw[1]=v.y; xw[2]=v.z; xw[3]=v.w;
        } else {
            float in[CIN1 + CIN2];
            {
                const float cnt = 1.f / (32.f * CIN1);
                float m  = st1[k] * cnt;
                float ms = st1[NN + k] * cnt;
                float iv = rsqrtf(ms - m*m + 1e-5f);
                const float4 v = *(const float4*)(src1 + ((size_t)b*NN + k) * CIN1);
                in[0]=(v.x-m)*iv; in[1]=(v.y-m)*iv; in[2]=(v.z-m)*iv; in[3]=(v.w-m)*iv;
            }
            if constexpr (CIN2 > 0) {
                const float cnt = 1.f / (32.f * CIN2);
                float m  = st2[k] * cnt;
                float ms = st2[NN + k] * cnt;
                float iv = rsqrtf(ms - m*m + 1e-5f);
                const float2 v = *(const float2*)(src2 + ((size_t)b*NN + k) * CIN2);
                in[CIN1+0]=(v.x-m)*iv; in[CIN1+1]=(v.y-m)*iv;
            }
            #pragma unroll
            for (int c = 0; c < COUT; ++c) {
                float s = 0.f;
                #pragma unroll
                for (int i = 0; i < CIN1+CIN2; ++i) s += in[i]*W[i*COUT+c];
                xw[c] = s;
            }
        }
        const float dk = dd[(size_t)b*NN + k];
        const int mk = k + ((k>>5)<<2);
        #pragma unroll
        for (int c = 0; c < COUT; ++c) XP[c][mk] = xw[c]*dk;
    }
    __syncthreads();

    // ---- main: 8 waves x 4 groups x 4 jammed rows ----
    const int lane = tid & 63, wid = tid >> 6;
    for (int g = 0; g < 4; ++g) {
        const int r0 = t0 + wid*16 + g*4;
        float acc[4][COUT];
        #pragma unroll
        for (int j = 0; j < 4; ++j)
            #pragma unroll
            for (int c = 0; c < COUT; ++c) acc[j][c] = 0.f;
        float dn[4]; size_t rb[4];
        #pragma unroll
        for (int j = 0; j < 4; ++j) {
            dn[j] = dd[(size_t)b*NN + r0 + j];
            rb[j] = ((size_t)(b*NN + r0 + j)) * NN;
        }

        if constexpr (HALFA) {
            #pragma unroll
            for (int it = 0; it < 2; ++it) {
                const int kw = 8 * (lane + 64 * it);
                const int mb = kw + ((kw >> 5) << 2);
                float xwv[COUT][8];
                #pragma unroll
                for (int c = 0; c < COUT; ++c) {
                    const float4 lo = *(const float4*)&XP[c][mb];
                    const float4 hi = *(const float4*)&XP[c][mb + 4];
                    xwv[c][0]=lo.x; xwv[c][1]=lo.y; xwv[c][2]=lo.z; xwv[c][3]=lo.w;
                    xwv[c][4]=hi.x; xwv[c][5]=hi.y; xwv[c][6]=hi.z; xwv[c][7]=hi.w;
                }
                #pragma unroll
                for (int j = 0; j < 4; ++j) {
                    const float4 rv = *(const float4*)(ah + rb[j] + kw);
                    const __half2* hp = (const __half2*)&rv;
                    float a8[8];
                    #pragma unroll
                    for (int q = 0; q < 4; ++q) {
                        const float2 f = __half22float2(hp[q]);
                        a8[2*q] = f.x; a8[2*q+1] = f.y;
                    }
                    #pragma unroll
                    for (int c = 0; c < COUT; ++c) {
                        float s = acc[j][c];
                        #pragma unroll
                        for (int q = 0; q < 8; ++q) s = fmaf(a8[q], xwv[c][q], s);
                        acc[j][c] = s;
                    }
                }
            }
        } else {
            #pragma unroll
            for (int it = 0; it < 4; ++it) {
                const int kw = 4 * (lane + 64 * it);
                const int mb = kw + ((kw >> 5) << 2);
                float xwv[COUT][4];
                #pragma unroll
                for (int c = 0; c < COUT; ++c) {
                    const float4 v = *(const float4*)&XP[c][mb];
                    xwv[c][0]=v.x; xwv[c][1]=v.y; xwv[c][2]=v.z; xwv[c][3]=v.w;
                }
                #pragma unroll
                for (int j = 0; j < 4; ++j) {
                    const int rr = r0 + j;
                    float4 a = *(const float4*)(adj + rb[j] + kw);
                    a.x = (kw + 0 == rr) ? 1.f : a.x;
                    a.y = (kw + 1 == rr) ? 1.f : a.y;
                    a.z = (kw + 2 == rr) ? 1.f : a.z;
                    a.w = (kw + 3 == rr) ? 1.f : a.w;
                    #pragma unroll
                    for (int c = 0; c < COUT; ++c) {
                        float s = acc[j][c];
                        s = fmaf(a.x, xwv[c][0], s);
                        s = fmaf(a.y, xwv[c][1], s);
                        s = fmaf(a.z, xwv[c][2], s);
                        s = fmaf(a.w, xwv[c][3], s);
                        acc[j][c] = s;
                    }
                }
            }
        }

        // ---- epilogue: wave reduce, relu, store Y, atomic BN stats ----
        #pragma unroll
        for (int j = 0; j < 4; ++j) {
            #pragma unroll
            for (int c = 0; c < COUT; ++c) {
                float v = acc[j][c];
                #pragma unroll
                for (int m = 1; m < 64; m <<= 1) v += __shfl_xor(v, m);
                acc[j][c] = v;
            }
            if (lane == 0) {
                float s = 0.f, q = 0.f;
                #pragma unroll
                for (int c = 0; c < COUT; ++c) {
                    float y = acc[j][c] * dn[j] + bias[c];
                    y = fmaxf(y, 0.f);
                    Y[((size_t)(b*NN + r0 + j)) * COUT + c] = y;
                    s += y; q += y * y;
                }
                atomicAdd(stout + (r0 + j), s);
                atomicAdd(stout + NN + (r0 + j), q);
            }
        }
    }
}

// ------------------------------------------------------------------
__global__ __launch_bounds__(NTHR)
void fused_all(KParams p)
{
    __shared__ float XP[4][NN + (NN/32)*4];
    __shared__ float red[8][24];
    __shared__ float pooled[24];

    const int bid = blockIdx.x, tid = threadIdx.x;
    const int lane = tid & 63, wid = tid >> 6;

    float* dd    = p.wsf + F_D;
    float* stats = p.wsf + F_STATS;
    float* xw1   = p.wsf + F_XW1;
    float* Yv[8];
    #pragma unroll
    for (int i = 0; i < 8; ++i) Yv[i] = p.wsf + F_Y[i];

    // ---- phase 0: degree + fp16 ah + XW1 + stats zero ----
    {
        const int rbase = bid * 128 + wid * 16;
        for (int i = 0; i < 16; ++i) {
            const int row = rbase + i;               // b*1024+n
            const int n = row & (NN - 1);
            const float4* arow = (const float4*)(p.adj + (size_t)row * NN);
            uint2* hrow = (uint2*)(p.ah + (size_t)row * NN);
            float s = 0.f;
            #pragma unroll
            for (int it = 0; it < 4; ++it) {
                const int idx = lane + it * 64;
                float4 v = arow[idx];
                const int k0 = idx * 4;
                v.x = (k0 + 0 == n) ? 1.f : v.x;
                v.y = (k0 + 1 == n) ? 1.f : v.y;
                v.z = (k0 + 2 == n) ? 1.f : v.z;
                v.w = (k0 + 3 == n) ? 1.f : v.w;
                s += v.x + v.y + v.z + v.w;
                if (p.use_half) {
                    __half2 h01 = __floats2half2_rn(v.x, v.y);
                    __half2 h23 = __floats2half2_rn(v.z, v.w);
                    uint2 u;
                    u.x = *(unsigned*)&h01; u.y = *(unsigned*)&h23;
                    hrow[idx] = u;
                }
            }
            #pragma unroll
            for (int m = 1; m < 64; m <<= 1) s += __shfl_xor(s, m);
            if (lane == 0) dd[row] = rsqrtf(fmaxf(s, 1.f));
        }
        if (tid < 128) {
            const int node = bid * 128 + tid;
            const float4* xr = (const float4*)(p.x + (size_t)node * 32);
            float in[32];
            #pragma unroll
            for (int i = 0; i < 8; ++i) {
                float4 v = xr[i];
                in[4*i]=v.x; in[4*i+1]=v.y; in[4*i+2]=v.z; in[4*i+3]=v.w;
            }
            float o[4] = {0.f,0.f,0.f,0.f};
            #pragma unroll
            for (int i = 0; i < 32; ++i)
                #pragma unroll
                for (int c = 0; c < 4; ++c) o[c] += in[i] * p.W1[i*4+c];
            *(float4*)(xw1 + (size_t)node * 4) = make_float4(o[0],o[1],o[2],o[3]);
        }
        if (tid < 64) stats[bid*64 + tid] = 0.f;
    }
    cg::this_grid().sync();

    #define STT(i) (stats + (i)*2048)
    if (p.use_half) {
        do_pass<0,0,4,true>(bid,tid, nullptr, p.ah, dd, xw1,
            nullptr,nullptr,nullptr,nullptr, nullptr, p.b1, Yv[0], STT(0), XP);
        cg::this_grid().sync();
        do_pass<4,0,2,true>(bid,tid, nullptr, p.ah, dd, nullptr,
            Yv[0],STT(0), nullptr,nullptr, p.W2, p.b2, Yv[1], STT(1), XP);
        cg::this_grid().sync();
        do_pass<4,2,4,true>(bid,tid, nullptr, p.ah, dd, nullptr,
            Yv[0],STT(0), Yv[1],STT(1), p.W3, p.b3, Yv[2], STT(2), XP);
        cg::this_grid().sync();
        do_pass<4,0,2,true>(bid,tid, nullptr, p.ah, dd, nullptr,
            Yv[2],STT(2), nullptr,nullptr, p.W2, p.b2, Yv[3], STT(3), XP);
        cg::this_grid().sync();
        do_pass<4,2,4,true>(bid,tid, nullptr, p.ah, dd, nullptr,
            Yv[2],STT(2), Yv[3],STT(3), p.W5, p.b5, Yv[4], STT(4), XP);
        cg::this_grid().sync();
        do_pass<4,0,2,true>(bid,tid, nullptr, p.ah, dd, nullptr,
            Yv[4],STT(4), nullptr,nullptr, p.W2, p.b2, Yv[5], STT(5), XP);
        cg::this_grid().sync();
        do_pass<4,2,4,true>(bid,tid, nullptr, p.ah, dd, nullptr,
            Yv[4],STT(4), Yv[5],STT(5), p.W7, p.b7, Yv[6], STT(6), XP);
        cg::this_grid().sync();
        do_pass<4,0,2,true>(bid,tid, nullptr, p.ah, dd, nullptr,
            Yv[6],STT(6), nullptr,nullptr, p.W2, p.b2, Yv[7], STT(7), XP);
        cg::this_grid().sync();
    } else {
        do_pass<0,0,4,false>(bid,tid, p.adj, nullptr, dd, xw1,
            nullptr,nullptr,nullptr,nullptr, nullptr, p.b1, Yv[0], STT(0), XP);
        cg::this_grid().sync();
        do_pass<4,0,2,false>(bid,tid, p.adj, nullptr, dd, nullptr,
            Yv[0],STT(0), nullptr,nullptr, p.W2, p.b2, Yv[1], STT(1), XP);
        cg::this_grid().sync();
        do_pass<4,2,4,false>(bid,tid, p.adj, nullptr, dd, nullptr,
            Yv[0],STT(0), Yv[1],STT(1), p.W3, p.b3, Yv[2], STT(2), XP);
        cg::this_grid().sync();
        do_pass<4,0,2,false>(bid,tid, p.adj, nullptr, dd, nullptr,
            Yv[2],STT(2), nullptr,nullptr, p.W2, p.b2, Yv[3], STT(3), XP);
        cg::this_grid().sync();
        do_pass<4,2,4,false>(bid,tid, p.adj, nullptr, dd, nullptr,
            Yv[2],STT(2), Yv[3],STT(3), p.W5, p.b5, Yv[4], STT(4), XP);
        cg::this_grid().sync();
        do_pass<4,0,2,false>(bid,tid, p.adj, nullptr, dd, nullptr,
            Yv[4],STT(4), nullptr,nullptr, p.W2, p.b2, Yv[5], STT(5), XP);
        cg::this_grid().sync();
        do_pass<4,2,4,false>(bid,tid, p.adj, nullptr, dd, nullptr,
            Yv[4],STT(4), Yv[5],STT(5), p.W7, p.b7, Yv[6], STT(6), XP);
        cg::this_grid().sync();
        do_pass<4,0,2,false>(bid,tid, p.adj, nullptr, dd, nullptr,
            Yv[6],STT(6), nullptr,nullptr, p.W2, p.b2, Yv[7], STT(7), XP);
        cg::this_grid().sync();
    }

    // ---- pooling + final linear (blocks 0..31, one per batch) ----
    if (bid < NB) {
        const int b = bid;
        const float* Ya[4] = {Yv[0], Yv[2], Yv[4], Yv[6]};
        const float* Yb[4] = {Yv[1], Yv[3], Yv[5], Yv[7]};
        float mx[24];
        #pragma unroll
        for (int i = 0; i < 24; ++i) mx[i] = -3.4e38f;

        for (int n = tid; n < NN; n += NTHR) {
            #pragma unroll
            for (int g = 0; g < 4; ++g) {
                {
                    const float* st = STT(2*g);
                    const float cnt = 1.f / 128.f;
                    float m  = st[n] * cnt;
                    float ms = st[NN + n] * cnt;
                    float iv = rsqrtf(ms - m*m + 1e-5f);
                    const float4 v = *(const float4*)(Ya[g] + ((size_t)b*NN + n) * 4);
                    mx[g*6+0] = fmaxf(mx[g*6+0], (v.x - m) * iv);
                    mx[g*6+1] = fmaxf(mx[g*6+1], (v.y - m) * iv);
                    mx[g*6+2] = fmaxf(mx[g*6+2], (v.z - m) * iv);
                    mx[g*6+3] = fmaxf(mx[g*6+3], (v.w - m) * iv);
                }
                {
                    const float* st = STT(2*g+1);
                    const float cnt = 1.f / 64.f;
                    float m  = st[n] * cnt;
                    float ms = st[NN + n] * cnt;
                    float iv = rsqrtf(ms - m*m + 1e-5f);
                    const float2 v = *(const float2*)(Yb[g] + ((size_t)b*NN + n) * 2);
                    mx[g*6+4] = fmaxf(mx[g*6+4], (v.x - m) * iv);
                    mx[g*6+5] = fmaxf(mx[g*6+5], (v.y - m) * iv);
                }
            }
        }
        #pragma unroll
        for (int i = 0; i < 24; ++i) {
            float v = mx[i];
            #pragma unroll
            for (int m = 1; m < 64; m <<= 1) v = fmaxf(v, __shfl_xor(v, m));
            mx[i] = v;
        }
        if (lane == 0) {
            #pragma unroll
            for (int i = 0; i < 24; ++i) red[wid][i] = mx[i];
        }
        __syncthreads();
        if (tid < 24) {
            float v = red[0][tid];
            #pragma unroll
            for (int w = 1; w < 8; ++w) v = fmaxf(v, red[w][tid]);
            pooled[tid] = v;
        }
        __syncthreads();
        if (tid < 3) {
            float s = p.bl[tid];
            #pragma unroll
            for (int c = 0; c < 24; ++c) s += pooled[c] * p.Wl[c*3 + tid];
            p.out[b*3 + tid] = s;
        }
    }
    #undef STT
}

// ------------------------------------------------------------------
extern "C" void kernel_launch(void* const* d_in, const int* in_sizes, int n_in,
                              void* d_out, int out_size, void* d_ws, size_t ws_size,
                              hipStream_t stream)
{
    KParams p;
    p.x   = (const float*)d_in[0];
    p.adj = (const float*)d_in[1];
    p.W1  = (const float*)d_in[2];
    p.b1  = (const float*)d_in[3];
    p.W2  = (const float*)d_in[4];
    p.b2  = (const float*)d_in[5];
    p.W3  = (const float*)d_in[6];
    p.b3  = (const float*)d_in[7];
    p.W5  = (const float*)d_in[8];
    p.b5  = (const float*)d_in[9];
    p.W7  = (const float*)d_in[10];
    p.b7  = (const float*)d_in[11];
    p.Wl  = (const float*)d_in[12];
    p.bl  = (const float*)d_in[13];
    p.out = (float*)d_out;
    p.wsf = (float*)d_ws;
    p.ah  = (__half*)((char*)d_ws + AH_BYTE_OFF);
    p.use_half = (ws_size >= WS_NEED_HALF) ? 1 : 0;

    void* kargs[] = { (void*)&p };
    hipLaunchCooperativeKernel((const void*)fused_all, dim3(NBLK), dim3(NTHR),
                               kargs, 0, stream);
}

// Round 5
// 402.939 us; speedup vs baseline: 1.1713x; 1.1713x over previous
//
#include <hip/hip_runtime.h>
#include <hip/hip_fp16.h>
#include <hip/hip_cooperative_groups.h>

namespace cg = cooperative_groups;

#define NB   32
#define NN   1024
#define NBLK 256
#define NTHR 1024

typedef _Float16 h2 __attribute__((ext_vector_type(2)));
typedef _Float16 h8 __attribute__((ext_vector_type(8)));

// ---------------- ws layout (floats) ----------------
static const size_t F_D     = 0;        // 32768  : rsqrt degree [B,N]
static const size_t F_STATS = 32768;    // 16384  : 8 x {sum[1024], sumsq[1024]}
static const size_t F_XW1   = 49152;    // 131072 : x @ W1 [B,N,4]
static constexpr size_t F_Y[8] = {180224, 311296, 376832, 507904,
                                  573440, 704512, 770048, 901120};

struct KParams {
    const float *adj, *x, *W1, *b1, *W2, *b2, *W3, *b3, *W5, *b5, *W7, *b7, *Wl, *bl;
    float* out;
    float* wsf;
};

__device__ __forceinline__ float fdot2f(h2 a, h2 b, float c) {
#if __has_builtin(__builtin_amdgcn_fdot2)
    return __builtin_amdgcn_fdot2(a, b, c, false);
#else
    return c + (float)a[0]*(float)b[0] + (float)a[1]*(float)b[1];
#endif
}

// ------------------------------------------------------------------
// One propagation pass. Lane-group layout: lane = 16*g + l (g<4, l<16).
// Wave wv owns rows n0 = slab + wv*8 + g*2 + {0,1}; lane l holds k-range
// k = 8*(l+16*it)+[0,8) per row in registers (A, fp16, diag=1, raw adj).
// Anorm = dn[r] * A * dk ; dk folded into LDS XPh tile, dn at epilogue.
// XPh padded: m(k) = k + 8*(k>>6) -> <=2-way bank conflict on h8 reads.
template<int CIN1, int CIN2, int COUT>
__device__ __forceinline__ void do_pass(
    const int b, const int n0, const int tid, const int l,
    const float* __restrict__ dd, const float* __restrict__ xw1,
    const float* __restrict__ src1, const float* __restrict__ st1,
    const float* __restrict__ src2, const float* __restrict__ st2,
    const float* __restrict__ W, const float* __restrict__ bias,
    float* __restrict__ Y, float* __restrict__ stout,
    const h2 (&A)[2][8][4], const float (&dn)[2],
    _Float16 (&XPh)[4][1152])
{
    // ---- prologue: one k per thread (NTHR == NN) ----
    {
        const int k = tid;
        float xw[COUT];
        if constexpr (CIN1 == 0) {
            const float4 v = *(const float4*)(xw1 + ((size_t)b*NN + k) * 4);
            xw[0]=v.x; xw[1]=v.y; xw[2]=v.z; xw[3]=v.w;
        } else {
            float in[CIN1 + CIN2];
            {
                const float cnt = 1.f / (32.f * CIN1);
                const float m  = st1[k] * cnt;
                const float ms = st1[NN + k] * cnt;
                const float iv = rsqrtf(ms - m*m + 1e-5f);
                const float4 v = *(const float4*)(src1 + ((size_t)b*NN + k) * CIN1);
                in[0]=(v.x-m)*iv; in[1]=(v.y-m)*iv; in[2]=(v.z-m)*iv; in[3]=(v.w-m)*iv;
            }
            if constexpr (CIN2 > 0) {
                const float cnt = 1.f / (32.f * CIN2);
                const float m  = st2[k] * cnt;
                const float ms = st2[NN + k] * cnt;
                const float iv = rsqrtf(ms - m*m + 1e-5f);
                const float2 v = *(const float2*)(src2 + ((size_t)b*NN + k) * CIN2);
                in[CIN1+0]=(v.x-m)*iv; in[CIN1+1]=(v.y-m)*iv;
            }
            #pragma unroll
            for (int c = 0; c < COUT; ++c) {
                float s = 0.f;
                #pragma unroll
                for (int i = 0; i < CIN1+CIN2; ++i) s += in[i]*W[i*COUT+c];
                xw[c] = s;
            }
        }
        const float dk = dd[b*NN + k];
        const int mk = k + ((k>>6)<<3);
        #pragma unroll
        for (int c = 0; c < COUT; ++c) XPh[c][mk] = (_Float16)(xw[c]*dk);
    }
    __syncthreads();

    // ---- main: fdot2 from registers ----
    float acc[2][COUT];
    #pragma unroll
    for (int r = 0; r < 2; ++r)
        #pragma unroll
        for (int c = 0; c < COUT; ++c) acc[r][c] = 0.f;

    #pragma unroll
    for (int it = 0; it < 8; ++it) {
        const int mb = 8*l + ((l>>3)<<3) + 144*it;
        h8 xv[COUT];
        #pragma unroll
        for (int c = 0; c < COUT; ++c) xv[c] = *(const h8*)&XPh[c][mb];
        #pragma unroll
        for (int r = 0; r < 2; ++r) {
            #pragma unroll
            for (int c = 0; c < COUT; ++c) {
                float s = acc[r][c];
                #pragma unroll
                for (int q = 0; q < 4; ++q) {
                    const h2 xq = {xv[c][2*q], xv[c][2*q+1]};
                    s = fdot2f(A[r][it][q], xq, s);
                }
                acc[r][c] = s;
            }
        }
    }

    // ---- 16-lane reduce + epilogue ----
    #pragma unroll
    for (int r = 0; r < 2; ++r) {
        #pragma unroll
        for (int c = 0; c < COUT; ++c) {
            float v = acc[r][c];
            v += __shfl_xor(v, 1); v += __shfl_xor(v, 2);
            v += __shfl_xor(v, 4); v += __shfl_xor(v, 8);
            acc[r][c] = v;
        }
    }
    if (l == 0) {
        #pragma unroll
        for (int r = 0; r < 2; ++r) {
            float s = 0.f, q2 = 0.f;
            #pragma unroll
            for (int c = 0; c < COUT; ++c) {
                float y = acc[r][c] * dn[r] + bias[c];
                y = fmaxf(y, 0.f);
                Y[((size_t)(b*NN + n0 + r)) * COUT + c] = y;
                s += y; q2 += y*y;
            }
            atomicAdd(stout + (n0 + r), s);
            atomicAdd(stout + NN + (n0 + r), q2);
        }
    }
}

// ------------------------------------------------------------------
__global__ __launch_bounds__(NTHR, 4)
void fused_all(KParams p)
{
    __shared__ _Float16 XPh[4][1152];   // 9216 B
    __shared__ float red[16][24];
    __shared__ float pooled[24];

    const int bid = blockIdx.x, tid = threadIdx.x;
    const int wv = tid >> 6, lane = tid & 63;
    const int g = lane >> 4, l = lane & 15;
    const int b = bid >> 3;              // 32 batches x 8 slabs
    const int slab = (bid & 7) << 7;     // 128 rows per block
    const int n0 = slab + wv*8 + g*2;    // this thread's 2 rows

    float* dd    = p.wsf + F_D;
    float* stats = p.wsf + F_STATS;
    float* xw1   = p.wsf + F_XW1;
    float* Yv[8];
    #pragma unroll
    for (int i = 0; i < 8; ++i) Yv[i] = p.wsf + F_Y[i];

    h2 A[2][8][4];      // 64 VGPRs: 2 rows x 64 halves of fp16 adj(diag=1)
    float dn[2];

    // ---- phase 0: load A to registers, degree, xw1, stats zero ----
    #pragma unroll
    for (int r = 0; r < 2; ++r) {
        const int n = n0 + r;
        const size_t rb = ((size_t)(b*NN + n)) * NN;
        float s = 0.f;
        #pragma unroll
        for (int it = 0; it < 8; ++it) {
            const int k0 = 8*(l + 16*it);
            float4 va = *(const float4*)(p.adj + rb + k0);
            float4 vb = *(const float4*)(p.adj + rb + k0 + 4);
            if (k0+0 == n) va.x = 1.f;
            if (k0+1 == n) va.y = 1.f;
            if (k0+2 == n) va.z = 1.f;
            if (k0+3 == n) va.w = 1.f;
            if (k0+4 == n) vb.x = 1.f;
            if (k0+5 == n) vb.y = 1.f;
            if (k0+6 == n) vb.z = 1.f;
            if (k0+7 == n) vb.w = 1.f;
            s += (va.x+va.y)+(va.z+va.w)+(vb.x+vb.y)+(vb.z+vb.w);
            A[r][it][0] = h2{(_Float16)va.x, (_Float16)va.y};
            A[r][it][1] = h2{(_Float16)va.z, (_Float16)va.w};
            A[r][it][2] = h2{(_Float16)vb.x, (_Float16)vb.y};
            A[r][it][3] = h2{(_Float16)vb.z, (_Float16)vb.w};
        }
        s += __shfl_xor(s, 1); s += __shfl_xor(s, 2);
        s += __shfl_xor(s, 4); s += __shfl_xor(s, 8);
        dn[r] = rsqrtf(fmaxf(s, 1.f));
        if (l == 0) dd[b*NN + n] = dn[r];
    }
    if (tid < 128) {
        const int node = b*NN + slab + tid;
        const float4* xr = (const float4*)(p.x + (size_t)node * 32);
        float in[32];
        #pragma unroll
        for (int i = 0; i < 8; ++i) {
            const float4 v = xr[i];
            in[4*i]=v.x; in[4*i+1]=v.y; in[4*i+2]=v.z; in[4*i+3]=v.w;
        }
        float o[4] = {0.f,0.f,0.f,0.f};
        #pragma unroll
        for (int i = 0; i < 32; ++i)
            #pragma unroll
            for (int c = 0; c < 4; ++c) o[c] += in[i] * p.W1[i*4+c];
        *(float4*)(xw1 + (size_t)node * 4) = make_float4(o[0],o[1],o[2],o[3]);
    }
    if (tid < 64) stats[bid*64 + tid] = 0.f;

    cg::grid_group grid = cg::this_grid();
    grid.sync();

    #define STT(i) (stats + (i)*2048)
    do_pass<0,0,4>(b, n0, tid, l, dd, xw1, nullptr,nullptr, nullptr,nullptr,
                   nullptr, p.b1, Yv[0], STT(0), A, dn, XPh);
    grid.sync();
    do_pass<4,0,2>(b, n0, tid, l, dd, nullptr, Yv[0],STT(0), nullptr,nullptr,
                   p.W2, p.b2, Yv[1], STT(1), A, dn, XPh);
    grid.sync();
    do_pass<4,2,4>(b, n0, tid, l, dd, nullptr, Yv[0],STT(0), Yv[1],STT(1),
                   p.W3, p.b3, Yv[2], STT(2), A, dn, XPh);
    grid.sync();
    do_pass<4,0,2>(b, n0, tid, l, dd, nullptr, Yv[2],STT(2), nullptr,nullptr,
                   p.W2, p.b2, Yv[3], STT(3), A, dn, XPh);
    grid.sync();
    do_pass<4,2,4>(b, n0, tid, l, dd, nullptr, Yv[2],STT(2), Yv[3],STT(3),
                   p.W5, p.b5, Yv[4], STT(4), A, dn, XPh);
    grid.sync();
    do_pass<4,0,2>(b, n0, tid, l, dd, nullptr, Yv[4],STT(4), nullptr,nullptr,
                   p.W2, p.b2, Yv[5], STT(5), A, dn, XPh);
    grid.sync();
    do_pass<4,2,4>(b, n0, tid, l, dd, nullptr, Yv[4],STT(4), Yv[5],STT(5),
                   p.W7, p.b7, Yv[6], STT(6), A, dn, XPh);
    grid.sync();
    do_pass<4,0,2>(b, n0, tid, l, dd, nullptr, Yv[6],STT(6), nullptr,nullptr,
                   p.W2, p.b2, Yv[7], STT(7), A, dn, XPh);
    grid.sync();

    // ---- pooling + final linear (blocks 0..31, one per batch) ----
    if (bid < NB) {
        const int bb = bid;
        const float* Ya[4] = {Yv[0], Yv[2], Yv[4], Yv[6]};
        const float* Yb[4] = {Yv[1], Yv[3], Yv[5], Yv[7]};
        float mx[24];
        #pragma unroll
        for (int i = 0; i < 24; ++i) mx[i] = -3.4e38f;

        for (int n = tid; n < NN; n += NTHR) {
            #pragma unroll
            for (int gg = 0; gg < 4; ++gg) {
                {
                    const float* st = STT(2*gg);
                    const float cnt = 1.f / 128.f;
                    const float m  = st[n] * cnt;
                    const float ms = st[NN + n] * cnt;
                    const float iv = rsqrtf(ms - m*m + 1e-5f);
                    const float4 v = *(const float4*)(Ya[gg] + ((size_t)bb*NN + n) * 4);
                    mx[gg*6+0] = fmaxf(mx[gg*6+0], (v.x - m) * iv);
                    mx[gg*6+1] = fmaxf(mx[gg*6+1], (v.y - m) * iv);
                    mx[gg*6+2] = fmaxf(mx[gg*6+2], (v.z - m) * iv);
                    mx[gg*6+3] = fmaxf(mx[gg*6+3], (v.w - m) * iv);
                }
                {
                    const float* st = STT(2*gg+1);
                    const float cnt = 1.f / 64.f;
                    const float m  = st[n] * cnt;
                    const float ms = st[NN + n] * cnt;
                    const float iv = rsqrtf(ms - m*m + 1e-5f);
                    const float2 v = *(const float2*)(Yb[gg] + ((size_t)bb*NN + n) * 2);
                    mx[gg*6+4] = fmaxf(mx[gg*6+4], (v.x - m) * iv);
                    mx[gg*6+5] = fmaxf(mx[gg*6+5], (v.y - m) * iv);
                }
            }
        }
        #pragma unroll
        for (int i = 0; i < 24; ++i) {
            float v = mx[i];
            #pragma unroll
            for (int m = 1; m < 64; m <<= 1) v = fmaxf(v, __shfl_xor(v, m));
            mx[i] = v;
        }
        if (lane == 0) {
            #pragma unroll
            for (int i = 0; i < 24; ++i) red[wv][i] = mx[i];
        }
        __syncthreads();
        if (tid < 24) {
            float v = red[0][tid];
            #pragma unroll
            for (int w = 1; w < 16; ++w) v = fmaxf(v, red[w][tid]);
            pooled[tid] = v;
        }
        __syncthreads();
        if (tid < 3) {
            float s = p.bl[tid];
            #pragma unroll
            for (int c = 0; c < 24; ++c) s += pooled[c] * p.Wl[c*3 + tid];
            p.out[bb*3 + tid] = s;
        }
    }
    #undef STT
}

// ------------------------------------------------------------------
extern "C" void kernel_launch(void* const* d_in, const int* in_sizes, int n_in,
                              void* d_out, int out_size, void* d_ws, size_t ws_size,
                              hipStream_t stream)
{
    KParams p;
    p.x   = (const float*)d_in[0];
    p.adj = (const float*)d_in[1];
    p.W1  = (const float*)d_in[2];
    p.b1  = (const float*)d_in[3];
    p.W2  = (const float*)d_in[4];
    p.b2  = (const float*)d_in[5];
    p.W3  = (const float*)d_in[6];
    p.b3  = (const float*)d_in[7];
    p.W5  = (const float*)d_in[8];
    p.b5  = (const float*)d_in[9];
    p.W7  = (const float*)d_in[10];
    p.b7  = (const float*)d_in[11];
    p.Wl  = (const float*)d_in[12];
    p.bl  = (const float*)d_in[13];
    p.out = (float*)d_out;
    p.wsf = (float*)d_ws;

    void* kargs[] = { (void*)&p };
    hipLaunchCooperativeKernel((const void*)fused_all, dim3(NBLK), dim3(NTHR),
                               kargs, 0, stream);
}

// Round 6
// 155.689 us; speedup vs baseline: 3.0314x; 2.5881x over previous
//
#include <hip/hip_runtime.h>
#include <hip/hip_fp16.h>

#define NB 32
#define NN 1024

typedef _Float16 h2 __attribute__((ext_vector_type(2)));
typedef _Float16 h8 __attribute__((ext_vector_type(8)));

// ---------------- ws layout (floats unless noted) ----------------
static const size_t F_D     = 0;        // 32768  : rsqrt degree [B,N]
static const size_t F_STATS = 32768;    // 16384  : 8 x {sum[1024], sumsq[1024]}
static const size_t F_XW1   = 49152;    // 131072 : x @ W1  [B,N,4]
static constexpr size_t F_Y[8] = {180224, 311296, 376832, 507904,
                                  573440, 704512, 770048, 901120};
static const size_t AH_BYTE_OFF  = 3866624;                 // fp16 adj(diag=1), 64MB
static const size_t WS_NEED_HALF = AH_BYTE_OFF + (size_t)NB*NN*NN*2;

__device__ __forceinline__ float fdot2f(h2 a, h2 b, float c) {
#if __has_builtin(__builtin_amdgcn_fdot2)
    return __builtin_amdgcn_fdot2(a, b, c, false);
#else
    return c + (float)a[0]*(float)b[0] + (float)a[1]*(float)b[1];
#endif
}

// ------------------------------------------------------------------
// K0: degree + write fp16 ah(diag=1) + XW1 precompute + stats zero
__global__ __launch_bounds__(256)
void k0_prep(const float* __restrict__ adj, const float* __restrict__ x,
             const float* __restrict__ W1, float* __restrict__ dd,
             float* __restrict__ xw1, float* __restrict__ stats,
             __half* __restrict__ ahw)
{
    const int tid = threadIdx.x;
    const int bx  = blockIdx.x;
    if (bx < 8192) {
        const int lane = tid & 63, wid = tid >> 6;
        const int row = bx * 4 + wid;          // b*1024+n
        const int n = row & (NN - 1);
        const float4* arow = (const float4*)(adj + (size_t)row * NN);
        uint2* hrow = (uint2*)(ahw + (size_t)row * NN);
        float s = 0.f;
        #pragma unroll
        for (int it = 0; it < 4; ++it) {
            const int idx = lane + it * 64;
            float4 v = arow[idx];
            const int k0 = idx * 4;
            v.x = (k0 + 0 == n) ? 1.f : v.x;
            v.y = (k0 + 1 == n) ? 1.f : v.y;
            v.z = (k0 + 2 == n) ? 1.f : v.z;
            v.w = (k0 + 3 == n) ? 1.f : v.w;
            s += v.x + v.y + v.z + v.w;
            if (ahw) {
                __half2 h01 = __floats2half2_rn(v.x, v.y);
                __half2 h23 = __floats2half2_rn(v.z, v.w);
                uint2 u;
                u.x = *(unsigned*)&h01; u.y = *(unsigned*)&h23;
                hrow[idx] = u;
            }
        }
        #pragma unroll
        for (int m = 1; m < 64; m <<= 1) s += __shfl_xor(s, m);
        if (lane == 0) dd[row] = rsqrtf(fmaxf(s, 1.f));
    } else if (bx < 8320) {
        const int id = (bx - 8192) * 256 + tid;   // b*1024+k
        const float4* xr = (const float4*)(x + (size_t)id * 32);
        float in[32];
        #pragma unroll
        for (int i = 0; i < 8; ++i) {
            float4 v = xr[i];
            in[4*i]=v.x; in[4*i+1]=v.y; in[4*i+2]=v.z; in[4*i+3]=v.w;
        }
        float o[4] = {0.f,0.f,0.f,0.f};
        #pragma unroll
        for (int i = 0; i < 32; ++i)
            #pragma unroll
            for (int c = 0; c < 4; ++c) o[c] += in[i] * W1[i*4+c];
        *(float4*)(xw1 + (size_t)id * 4) = make_float4(o[0],o[1],o[2],o[3]);
    } else {
        const int id = (bx - 8320) * 256 + tid;   // < 16384
        stats[id] = 0.f;
    }
}

// ------------------------------------------------------------------
// stage one 256-half k-chunk of this wave's 8 rows into LDS (32KB buffer,
// linear dest, source pre-swizzled col ^= (row&7)<<4 so swizzled reads are
// bank-spread). 4 x 1KB global_load_lds issues per wave.
__device__ __forceinline__ void stage_chunk(const __half* __restrict__ ah,
        int rowbase, int wid, int lane, int ck, char* sbuf)
{
    #pragma unroll
    for (int i = 0; i < 4; ++i) {
        const int ob = (wid << 12) + (i << 10);
        const int o  = ob + (lane << 4);
        const int row = o >> 9;                       // 0..63 tile row
        const int scol = (o & 511) ^ ((row & 7) << 4);
        const char* g = (const char*)ah +
            (((size_t)(rowbase + row)) * NN + (size_t)ck * 256) * 2 + scol;
#if __has_builtin(__builtin_amdgcn_global_load_lds)
        __builtin_amdgcn_global_load_lds(
            (const __attribute__((address_space(1))) void*)g,
            (__attribute__((address_space(3))) void*)(sbuf + ob),
            16, 0, 0);
#else
        *(float4*)(sbuf + o) = *(const float4*)g;
#endif
    }
}

// ------------------------------------------------------------------
// Pass kernel (fp16 staged): Y = relu(Anorm @ XW + b).
// Grid 512: b = bid>>4, tile = (bid&15)*64. 8 waves x 8 rows.
// Lane = rj*8+ll: row rj, k-slice ll (128 halves across 4 chunks).
template<int CIN1, int CIN2, int COUT>
__global__ __launch_bounds__(512, 4)
void pass_half(const __half* __restrict__ ah, const float* __restrict__ dd,
               const float* __restrict__ xw1,
               const float* __restrict__ src1, const float* __restrict__ st1,
               const float* __restrict__ src2, const float* __restrict__ st2,
               const float* __restrict__ W, const float* __restrict__ bias,
               float* __restrict__ Y, float* __restrict__ stout)
{
    __shared__ char sA[2][32768];
    __shared__ _Float16 XPh[COUT][1280];   // m(k)=k+8*(k>>5) padding
    const int tid = threadIdx.x, lane = tid & 63, wid = tid >> 6;
    const int b    = blockIdx.x >> 4;
    const int tile = (blockIdx.x & 15) << 6;
    const int rowbase = b * NN + tile;

    // issue chunk-0 staging immediately
    stage_chunk(ah, rowbase, wid, lane, 0, sA[0]);

    // ---- prologue: build fp16 XW tile (d[k] folded) ----
    for (int k = tid; k < NN; k += 512) {
        float xw[COUT];
        if constexpr (CIN1 == 0) {
            const float4 v = *(const float4*)(xw1 + ((size_t)b*NN + k) * 4);
            xw[0]=v.x; xw[1]=v.y; xw[2]=v.z; xw[3]=v.w;
        } else {
            float in[CIN1 + CIN2];
            {
                const float cnt = 1.f / (32.f * CIN1);
                const float m  = st1[k] * cnt;
                const float ms = st1[NN + k] * cnt;
                const float iv = rsqrtf(ms - m*m + 1e-5f);
                const float4 v = *(const float4*)(src1 + ((size_t)b*NN + k) * CIN1);
                in[0]=(v.x-m)*iv; in[1]=(v.y-m)*iv; in[2]=(v.z-m)*iv; in[3]=(v.w-m)*iv;
            }
            if constexpr (CIN2 > 0) {
                const float cnt = 1.f / (32.f * CIN2);
                const float m  = st2[k] * cnt;
                const float ms = st2[NN + k] * cnt;
                const float iv = rsqrtf(ms - m*m + 1e-5f);
                const float2 v = *(const float2*)(src2 + ((size_t)b*NN + k) * CIN2);
                in[CIN1+0]=(v.x-m)*iv; in[CIN1+1]=(v.y-m)*iv;
            }
            #pragma unroll
            for (int c = 0; c < COUT; ++c) {
                float s = 0.f;
                #pragma unroll
                for (int i = 0; i < CIN1+CIN2; ++i) s += in[i]*W[i*COUT+c];
                xw[c] = s;
            }
        }
        const float dk = dd[b*NN + k];
        const int mk = k + ((k>>5)<<3);
        #pragma unroll
        for (int c = 0; c < COUT; ++c) XPh[c][mk] = (_Float16)(xw[c]*dk);
    }
    asm volatile("s_waitcnt vmcnt(0)" ::: "memory");
    __syncthreads();

    // ---- main: 4 chunks, double-buffered ----
    const int rj = lane >> 3, ll = lane & 7;
    const int trow = (wid << 3) + rj;              // tile-local row 0..63
    float acc[COUT];
    #pragma unroll
    for (int c = 0; c < COUT; ++c) acc[c] = 0.f;

    int buf = 0;
    for (int ck = 0; ck < 4; ++ck) {
        if (ck < 3) stage_chunk(ah, rowbase, wid, lane, ck+1, sA[buf^1]);
        const char* aB = &sA[buf][trow << 9];
        #pragma unroll
        for (int sub = 0; sub < 4; ++sub) {
            const h8 av = *(const h8*)(aB + (((((ll<<2)+sub)) ^ rj) << 4));
            const int k = ck*256 + ll*32 + sub*8;
            const int mk = k + ((k>>5)<<3);
            #pragma unroll
            for (int c = 0; c < COUT; ++c) {
                const h8 xv = *(const h8*)&XPh[c][mk];
                float s = acc[c];
                s = fdot2f(h2{av[0],av[1]}, h2{xv[0],xv[1]}, s);
                s = fdot2f(h2{av[2],av[3]}, h2{xv[2],xv[3]}, s);
                s = fdot2f(h2{av[4],av[5]}, h2{xv[4],xv[5]}, s);
                s = fdot2f(h2{av[6],av[7]}, h2{xv[6],xv[7]}, s);
                acc[c] = s;
            }
        }
        asm volatile("s_waitcnt vmcnt(0)" ::: "memory");
        __syncthreads();
        buf ^= 1;
    }

    // ---- reduce over ll (lanes differing in low 3 bits) ----
    #pragma unroll
    for (int c = 0; c < COUT; ++c) {
        float v = acc[c];
        v += __shfl_xor(v, 1); v += __shfl_xor(v, 2); v += __shfl_xor(v, 4);
        acc[c] = v;
    }
    if (ll == 0) {
        const int n = tile + trow;
        const float dn = dd[b*NN + n];
        float s = 0.f, q2 = 0.f;
        float y[COUT];
        #pragma unroll
        for (int c = 0; c < COUT; ++c) {
            float t = acc[c] * dn + bias[c];
            t = fmaxf(t, 0.f);
            y[c] = t; s += t; q2 += t*t;
        }
        if constexpr (COUT == 4)
            *(float4*)(Y + ((size_t)(b*NN + n))*4) = make_float4(y[0],y[1],y[2],y[3]);
        else
            *(float2*)(Y + ((size_t)(b*NN + n))*2) = make_float2(y[0],y[1]);
        atomicAdd(stout + n, s);
        atomicAdd(stout + NN + n, q2);
    }
}

// ------------------------------------------------------------------
// Fallback fp32 pass (no ah): direct adj reads (R2-proven path).
template<int CIN1, int CIN2, int COUT>
__global__ __launch_bounds__(512)
void pass_f32(const float* __restrict__ adj, const float* __restrict__ dd,
              const float* __restrict__ xw1,
              const float* __restrict__ src1, const float* __restrict__ st1,
              const float* __restrict__ src2, const float* __restrict__ st2,
              const float* __restrict__ W, const float* __restrict__ bias,
              float* __restrict__ Y, float* __restrict__ stout)
{
    __shared__ float XP[COUT][NN + (NN/32)*4];
    const int tid  = threadIdx.x;
    const int b    = blockIdx.x >> 5;
    const int tile = (blockIdx.x & 31) * 32;

    for (int k = tid; k < NN; k += 512) {
        float xw[COUT];
        if constexpr (CIN1 == 0) {
            const float4 v = *(const float4*)(xw1 + ((size_t)b*NN + k) * 4);
            xw[0]=v.x; xw[1]=v.y; xw[2]=v.z; xw[3]=v.w;
        } else {
            float in[CIN1 + CIN2];
            {
                const float cnt = 1.f / (32.f * CIN1);
                float m  = st1[k] * cnt;
                float ms = st1[NN + k] * cnt;
                float iv = rsqrtf(ms - m*m + 1e-5f);
                const float4 v = *(const float4*)(src1 + ((size_t)b*NN + k) * CIN1);
                in[0]=(v.x-m)*iv; in[1]=(v.y-m)*iv; in[2]=(v.z-m)*iv; in[3]=(v.w-m)*iv;
            }
            if constexpr (CIN2 > 0) {
                const float cnt = 1.f / (32.f * CIN2);
                float m  = st2[k] * cnt;
                float ms = st2[NN + k] * cnt;
                float iv = rsqrtf(ms - m*m + 1e-5f);
                const float2 v = *(const float2*)(src2 + ((size_t)b*NN + k) * CIN2);
                in[CIN1+0]=(v.x-m)*iv; in[CIN1+1]=(v.y-m)*iv;
            }
            #pragma unroll
            for (int c = 0; c < COUT; ++c) {
                float s = 0.f;
                #pragma unroll
                for (int i = 0; i < CIN1+CIN2; ++i) s += in[i]*W[i*COUT+c];
                xw[c] = s;
            }
        }
        const float dk = dd[(size_t)b*NN + k];
        const int mk = k + ((k >> 5) << 2);
        #pragma unroll
        for (int c = 0; c < COUT; ++c) XP[c][mk] = xw[c]*dk;
    }
    __syncthreads();

    const int lane = tid & 63, wid = tid >> 6;
    const int r0 = tile + wid * 4;
    float acc[4][COUT];
    #pragma unroll
    for (int j = 0; j < 4; ++j)
        #pragma unroll
        for (int c = 0; c < COUT; ++c) acc[j][c] = 0.f;
    float dn[4]; size_t rb[4];
    #pragma unroll
    for (int j = 0; j < 4; ++j) {
        dn[j] = dd[(size_t)b*NN + r0 + j];
        rb[j] = ((size_t)(b*NN + r0 + j)) * NN;
    }
    #pragma unroll
    for (int it = 0; it < 4; ++it) {
        const int kw = 4 * (lane + 64 * it);
        const int mb = kw + ((kw >> 5) << 2);
        float xwv[COUT][4];
        #pragma unroll
        for (int c = 0; c < COUT; ++c) {
            const float4 v = *(const float4*)&XP[c][mb];
            xwv[c][0]=v.x; xwv[c][1]=v.y; xwv[c][2]=v.z; xwv[c][3]=v.w;
        }
        #pragma unroll
        for (int j = 0; j < 4; ++j) {
            const int rr = r0 + j;
            float4 a = *(const float4*)(adj + rb[j] + kw);
            a.x = (kw + 0 == rr) ? 1.f : a.x;
            a.y = (kw + 1 == rr) ? 1.f : a.y;
            a.z = (kw + 2 == rr) ? 1.f : a.z;
            a.w = (kw + 3 == rr) ? 1.f : a.w;
            #pragma unroll
            for (int c = 0; c < COUT; ++c) {
                float s = acc[j][c];
                s = fmaf(a.x, xwv[c][0], s); s = fmaf(a.y, xwv[c][1], s);
                s = fmaf(a.z, xwv[c][2], s); s = fmaf(a.w, xwv[c][3], s);
                acc[j][c] = s;
            }
        }
    }
    #pragma unroll
    for (int j = 0; j < 4; ++j) {
        #pragma unroll
        for (int c = 0; c < COUT; ++c) {
            float v = acc[j][c];
            #pragma unroll
            for (int m = 1; m < 64; m <<= 1) v += __shfl_xor(v, m);
            acc[j][c] = v;
        }
        if (lane == 0) {
            float s = 0.f, q = 0.f;
            #pragma unroll
            for (int c = 0; c < COUT; ++c) {
                float y = acc[j][c] * dn[j] + bias[c];
                y = fmaxf(y, 0.f);
                Y[((size_t)(b*NN + r0 + j)) * COUT + c] = y;
                s += y; q += y * y;
            }
            atomicAdd(stout + (r0 + j), s);
            atomicAdd(stout + NN + (r0 + j), q);
        }
    }
}

// ------------------------------------------------------------------
// Final: 4 max-pools over nodes + linear [B,24]@[24,3]+bl
__global__ __launch_bounds__(256)
void k_final(const float* __restrict__ Y1, const float* __restrict__ Y2,
             const float* __restrict__ Y3, const float* __restrict__ Y4,
             const float* __restrict__ Y5, const float* __restrict__ Y6,
             const float* __restrict__ Y7, const float* __restrict__ Y8,
             const float* __restrict__ stats,
             const float* __restrict__ Wl, const float* __restrict__ bl,
             float* __restrict__ out)
{
    const float* Ya[4] = {Y1, Y3, Y5, Y7};
    const float* Yb[4] = {Y2, Y4, Y6, Y8};
    const int b = blockIdx.x, tid = threadIdx.x;
    float mx[24];
    #pragma unroll
    for (int i = 0; i < 24; ++i) mx[i] = -3.4e38f;

    for (int n = tid; n < NN; n += 256) {
        #pragma unroll
        for (int g = 0; g < 4; ++g) {
            {
                const float* st = stats + (size_t)(2*g) * 2048;
                const float cnt = 1.f / 128.f;
                float m  = st[n] * cnt;
                float ms = st[NN + n] * cnt;
                float iv = rsqrtf(ms - m*m + 1e-5f);
                const float4 v = *(const float4*)(Ya[g] + ((size_t)b*NN + n) * 4);
                mx[g*6+0] = fmaxf(mx[g*6+0], (v.x - m) * iv);
                mx[g*6+1] = fmaxf(mx[g*6+1], (v.y - m) * iv);
                mx[g*6+2] = fmaxf(mx[g*6+2], (v.z - m) * iv);
                mx[g*6+3] = fmaxf(mx[g*6+3], (v.w - m) * iv);
            }
            {
                const float* st = stats + (size_t)(2*g+1) * 2048;
                const float cnt = 1.f / 64.f;
                float m  = st[n] * cnt;
                float ms = st[NN + n] * cnt;
                float iv = rsqrtf(ms - m*m + 1e-5f);
                const float2 v = *(const float2*)(Yb[g] + ((size_t)b*NN + n) * 2);
                mx[g*6+4] = fmaxf(mx[g*6+4], (v.x - m) * iv);
                mx[g*6+5] = fmaxf(mx[g*6+5], (v.y - m) * iv);
            }
        }
    }
    const int lane = tid & 63, wid = tid >> 6;
    #pragma unroll
    for (int i = 0; i < 24; ++i) {
        float v = mx[i];
        #pragma unroll
        for (int m = 1; m < 64; m <<= 1) v = fmaxf(v, __shfl_xor(v, m));
        mx[i] = v;
    }
    __shared__ float red[4][24];
    __shared__ float pooled[24];
    if (lane == 0) {
        #pragma unroll
        for (int i = 0; i < 24; ++i) red[wid][i] = mx[i];
    }
    __syncthreads();
    if (tid < 24)
        pooled[tid] = fmaxf(fmaxf(red[0][tid], red[1][tid]),
                            fmaxf(red[2][tid], red[3][tid]));
    __syncthreads();
    if (tid < 3) {
        float s = bl[tid];
        #pragma unroll
        for (int c = 0; c < 24; ++c) s += pooled[c] * Wl[c*3 + tid];
        out[b*3 + tid] = s;
    }
}

// ------------------------------------------------------------------
extern "C" void kernel_launch(void* const* d_in, const int* in_sizes, int n_in,
                              void* d_out, int out_size, void* d_ws, size_t ws_size,
                              hipStream_t stream)
{
    const float* x   = (const float*)d_in[0];
    const float* adj = (const float*)d_in[1];
    const float* W1  = (const float*)d_in[2];
    const float* b1  = (const float*)d_in[3];
    const float* W2  = (const float*)d_in[4];
    const float* b2  = (const float*)d_in[5];
    const float* W3  = (const float*)d_in[6];
    const float* b3  = (const float*)d_in[7];
    const float* W5  = (const float*)d_in[8];
    const float* b5  = (const float*)d_in[9];
    const float* W7  = (const float*)d_in[10];
    const float* b7  = (const float*)d_in[11];
    const float* Wl  = (const float*)d_in[12];
    const float* bl  = (const float*)d_in[13];
    float* out = (float*)d_out;

    float* wsf   = (float*)d_ws;
    float* dd    = wsf + F_D;
    float* stats = wsf + F_STATS;
    float* xw1   = wsf + F_XW1;
    float* Y[8];
    #pragma unroll
    for (int i = 0; i < 8; ++i) Y[i] = wsf + F_Y[i];
    __half* ah = (__half*)((char*)d_ws + AH_BYTE_OFF);
    const bool use_half = (ws_size >= WS_NEED_HALF);

    k0_prep<<<8384, 256, 0, stream>>>(adj, x, W1, dd, xw1, stats,
                                      use_half ? ah : nullptr);

    #define STT(i) (stats + (i)*2048)
    if (use_half) {
        const dim3 pg(512), pb(512);
        pass_half<0,0,4><<<pg, pb, 0, stream>>>(ah, dd, xw1,
            nullptr, nullptr, nullptr, nullptr, nullptr, b1, Y[0], STT(0));
        pass_half<4,0,2><<<pg, pb, 0, stream>>>(ah, dd, nullptr,
            Y[0], STT(0), nullptr, nullptr, W2, b2, Y[1], STT(1));
        pass_half<4,2,4><<<pg, pb, 0, stream>>>(ah, dd, nullptr,
            Y[0], STT(0), Y[1], STT(1), W3, b3, Y[2], STT(2));
        pass_half<4,0,2><<<pg, pb, 0, stream>>>(ah, dd, nullptr,
            Y[2], STT(2), nullptr, nullptr, W2, b2, Y[3], STT(3));
        pass_half<4,2,4><<<pg, pb, 0, stream>>>(ah, dd, nullptr,
            Y[2], STT(2), Y[3], STT(3), W5, b5, Y[4], STT(4));
        pass_half<4,0,2><<<pg, pb, 0, stream>>>(ah, dd, nullptr,
            Y[4], STT(4), nullptr, nullptr, W2, b2, Y[5], STT(5));
        pass_half<4,2,4><<<pg, pb, 0, stream>>>(ah, dd, nullptr,
            Y[4], STT(4), Y[5], STT(5), W7, b7, Y[6], STT(6));
        pass_half<4,0,2><<<pg, pb, 0, stream>>>(ah, dd, nullptr,
            Y[6], STT(6), nullptr, nullptr, W2, b2, Y[7], STT(7));
    } else {
        const dim3 pg(1024), pb(512);
        pass_f32<0,0,4><<<pg, pb, 0, stream>>>(adj, dd, xw1,
            nullptr, nullptr, nullptr, nullptr, nullptr, b1, Y[0], STT(0));
        pass_f32<4,0,2><<<pg, pb, 0, stream>>>(adj, dd, nullptr,
            Y[0], STT(0), nullptr, nullptr, W2, b2, Y[1], STT(1));
        pass_f32<4,2,4><<<pg, pb, 0, stream>>>(adj, dd, nullptr,
            Y[0], STT(0), Y[1], STT(1), W3, b3, Y[2], STT(2));
        pass_f32<4,0,2><<<pg, pb, 0, stream>>>(adj, dd, nullptr,
            Y[2], STT(2), nullptr, nullptr, W2, b2, Y[3], STT(3));
        pass_f32<4,2,4><<<pg, pb, 0, stream>>>(adj, dd, nullptr,
            Y[2], STT(2), Y[3], STT(3), W5, b5, Y[4], STT(4));
        pass_f32<4,0,2><<<pg, pb, 0, stream>>>(adj, dd, nullptr,
            Y[4], STT(4), nullptr, nullptr, W2, b2, Y[5], STT(5));
        pass_f32<4,2,4><<<pg, pb, 0, stream>>>(adj, dd, nullptr,
            Y[4], STT(4), Y[5], STT(5), W7, b7, Y[6], STT(6));
        pass_f32<4,0,2><<<pg, pb, 0, stream>>>(adj, dd, nullptr,
            Y[6], STT(6), nullptr, nullptr, W2, b2, Y[7], STT(7));
    }
    #undef STT

    k_final<<<32, 256, 0, stream>>>(Y[0], Y[1], Y[2], Y[3], Y[4], Y[5], Y[6], Y[7],
                                    stats, Wl, bl, out);
}